// Round 5
// baseline (584.981 us; speedup 1.0000x reference)
//
#include <hip/hip_runtime.h>
#include <hip/hip_cooperative_groups.h>

namespace cg = cooperative_groups;

#define N_DRUG 20000
#define N_PROT 8000
#define D_DRUG 300
#define D_PROT 1280
#define HIDDEN 512
#define OUT_D  5
#define N_EDGE 500000
#define N_LBL  200000
#define WLD    812        // W_lin leading dim (300+512)
#define AGG_S  8          // agg row stride (floats): [0..4]=mean, rest pad
#define PA_S   8          // P_A row stride (floats): 32B-aligned float4 gathers

// ---- mega-kernel decomposition ----
#define MEGA_GRID 1024                    // 4 blocks/CU co-resident (launch_bounds 256,4)
#define MPG 16                            // protein groups
#define MPROT_G (N_PROT / MPG)            // 500
#define MSL 32                            // edge slices
#define N_EDGE4 (N_EDGE / 4)              // 125000 int4 pairs
#define ME4_PER_S 3907                    // ceil(125000/32); last slice short (guarded)
#define MSCAN_VB (MPG * MSL)              // 512 scan virtual blocks
#define MPART_STRIDE (N_PROT * 6)         // 48000 floats per slice

// ---- legacy (round-4 proven fallback) decomposition ----
#define PGROUPS 16
#define PROT_PER_G (N_PROT / PGROUPS)     // 500
#define ESLICES 64
#define EDGE_PER_S 8192                   // 64*8192 = 524288 >= N_EDGE (tail guarded)
#define SCAN_B (PGROUPS * ESLICES)        // 1024
#define PART_STRIDE (N_PROT * 6)          // 48000 floats per slice

// =========================================================================
// MEGA: all 5 phases in ONE cooperative dispatch (kills 4 dispatch gaps +
// 5 ramp/drain tails; ~45us of structure -> ~25-30us).
//   A: fold A/B/c                 (248 vb)
//   B: drug proj -> P_A, drugO    (1250 vb)
//   C: edge-scan (512 vb, LDS agg, plain-stored slice partials)
//      || protO dense (2000 vb)
//   D: reduce 32 partials + mean  (200 vb, 240 lanes)
//   E: final gather-add           (782 vb)
// =========================================================================
__global__ __launch_bounds__(256, 4)
void k_mega(const float* __restrict__ x_drug, const float* __restrict__ x_prot,
            const int* __restrict__ edge_src, const int* __restrict__ edge_dst,
            const int* __restrict__ lbl_src, const int* __restrict__ lbl_dst,
            const float* __restrict__ W_l, const float* __restrict__ b_l,
            const float* __restrict__ W_r, const float* __restrict__ W_lin,
            const float* __restrict__ b_lin,
            float* __restrict__ A, float* __restrict__ B, float* __restrict__ c,
            float* __restrict__ P_A, float* __restrict__ drugO,
            float* __restrict__ protO, float* __restrict__ partial,
            float* __restrict__ agg, float* __restrict__ out) {
    cg::grid_group grid = cg::this_grid();
    int tid = threadIdx.x;
    __shared__ float smem[MPROT_G * 6];   // 12 KB, reused by phases C and D

    // ---------------- Phase A: fold ----------------
    for (int vb = blockIdx.x; vb < 248; vb += gridDim.x) {
        int t  = vb * 256 + tid;          // [0, 63488)
        int e  = t >> 3;                  // output element [0, 7936)
        int j  = t & 7;                   // h-chunk lane
        int h0 = j * 64;
        const int nA = OUT_D * D_DRUG;    // 1500
        const int nB = OUT_D * D_PROT;    // 6400
        float s = 0.f;
        if (e < nA) {
            int o = e / D_DRUG, k = e - o * D_DRUG;
            const float* wp = W_lin + o * WLD + D_DRUG + h0;
            const float* w  = W_l + (size_t)h0 * D_DRUG + k;
#pragma unroll 8
            for (int h = 0; h < 64; ++h) s += wp[h] * w[h * D_DRUG];
        } else if (e < nA + nB) {
            int u = e - nA;
            int o = u / D_PROT, k = u - o * D_PROT;
            const float* wp = W_lin + o * WLD + D_DRUG + h0;
            const float* w  = W_r + (size_t)h0 * D_PROT + k;
#pragma unroll 8
            for (int h = 0; h < 64; ++h) s += wp[h] * w[h * D_PROT];
        } else if (e < nA + nB + OUT_D) {
            int o = e - nA - nB;
            const float* wp = W_lin + o * WLD + D_DRUG + h0;
#pragma unroll 8
            for (int h = 0; h < 64; ++h) s += wp[h] * b_l[h0 + h];
        }
        s += __shfl_xor(s, 1, 64);
        s += __shfl_xor(s, 2, 64);
        s += __shfl_xor(s, 4, 64);
        if (j == 0) {
            if (e < nA)                     A[e] = s;
            else if (e < nA + nB)           B[e - nA] = s;
            else if (e < nA + nB + OUT_D)   c[e - nA - nB] = s;
        }
    }
    grid.sync();

    // ---------------- Phase B: drug projection ----------------
    for (int vb = blockIdx.x; vb < 1250; vb += gridDim.x) {
        int gid = vb * 256 + tid;
        int row = gid >> 4;               // 1250*256/16 = 20000 exactly
        int sub = tid & 15;
        const float4* xr = (const float4*)(x_drug + (size_t)row * D_DRUG);
        float acc[10];
#pragma unroll
        for (int i = 0; i < 10; ++i) acc[i] = 0.f;
        for (int k = sub; k < D_DRUG / 4; k += 16) {
            float4 x = xr[k];
#pragma unroll
            for (int o = 0; o < OUT_D; ++o) {
                float4 a = ((const float4*)(A + o * D_DRUG))[k];
                acc[o] += x.x * a.x + x.y * a.y + x.z * a.z + x.w * a.w;
                float4 w = ((const float4*)(W_lin + o * WLD))[k];
                acc[5 + o] += x.x * w.x + x.y * w.y + x.z * w.z + x.w * w.w;
            }
        }
#pragma unroll
        for (int i = 0; i < 10; ++i) {
            float v = acc[i];
            for (int m = 8; m; m >>= 1) v += __shfl_xor(v, m, 64);
            acc[i] = v;
        }
        if (sub < OUT_D) {
            P_A[(size_t)row * PA_S + sub]    = acc[sub];
            drugO[(size_t)row * OUT_D + sub] = acc[5 + sub] + b_lin[sub];
        } else if (sub < PA_S) {
            P_A[(size_t)row * PA_S + sub] = 0.f;
        }
    }
    grid.sync();

    // ---------------- Phase C: edge-scan || prot dense ----------------
    for (int vb = blockIdx.x; vb < MSCAN_VB + 2000; vb += gridDim.x) {
        if (vb < MSCAN_VB) {
            for (int i = tid; i < MPROT_G * 6; i += 256) smem[i] = 0.f;
            __syncthreads();
            int pg  = vb >> 5;            // [0,16)
            int sl  = vb & 31;            // [0,32)
            int plo = pg * MPROT_G;
            int e0_4 = sl * ME4_PER_S;
            int lim  = ME4_PER_S;         // per-slice int4 count (last slice short)
            if (e0_4 + lim > N_EDGE4) lim = N_EDGE4 - e0_4;
            const int4* dst4 = (const int4*)edge_dst;
            const int4* src4 = (const int4*)edge_src;
#define MACCUM(dd, ss) do {                                                  \
                int _d = (dd) - plo;                                         \
                if ((unsigned)_d < (unsigned)MPROT_G) {                      \
                    const float* pp = P_A + (size_t)(ss) * PA_S;             \
                    float4 p4 = *(const float4*)pp;                          \
                    float  p5 = pp[4];                                       \
                    float* L = smem + _d * 6;                                \
                    atomicAdd(L + 0, p4.x);                                  \
                    atomicAdd(L + 1, p4.y);                                  \
                    atomicAdd(L + 2, p4.z);                                  \
                    atomicAdd(L + 3, p4.w);                                  \
                    atomicAdd(L + 4, p5);                                    \
                    atomicAdd(L + 5, 1.0f);                                  \
                } } while (0)
#pragma unroll
            for (int it = 0; it < 16; ++it) {       // 16*256 = 4096 >= 3907
                int off = it * 256 + tid;
                if (off < lim) {
                    int4 d4 = dst4[e0_4 + off];
                    int4 s4 = src4[e0_4 + off];
                    MACCUM(d4.x, s4.x);
                    MACCUM(d4.y, s4.y);
                    MACCUM(d4.z, s4.z);
                    MACCUM(d4.w, s4.w);
                }
            }
#undef MACCUM
            __syncthreads();
            float* pout = partial + (size_t)sl * MPART_STRIDE + (size_t)plo * 6;
            for (int i = tid; i < MPROT_G * 6; i += 256) pout[i] = smem[i];
            __syncthreads();
        } else {
            int wave = ((vb - MSCAN_VB) * 256 + tid) >> 6;   // 2000*256/64 = 8000
            int lane = tid & 63;
            const float4* xr = (const float4*)(x_prot + (size_t)wave * D_PROT);
            float acc[OUT_D] = {0.f, 0.f, 0.f, 0.f, 0.f};
            for (int k = lane; k < D_PROT / 4; k += 64) {
                float4 x = xr[k];
#pragma unroll
                for (int o = 0; o < OUT_D; ++o) {
                    float4 bb = ((const float4*)(B + o * D_PROT))[k];
                    acc[o] += x.x * bb.x + x.y * bb.y + x.z * bb.z + x.w * bb.w;
                }
            }
#pragma unroll
            for (int o = 0; o < OUT_D; ++o) {
                float v = acc[o];
                for (int off = 32; off; off >>= 1) v += __shfl_xor(v, off, 64);
                acc[o] = v;
            }
            if (lane < OUT_D) protO[(size_t)wave * OUT_D + lane] = acc[lane] + c[lane];
        }
    }
    grid.sync();

    // ---------------- Phase D: reduce partials + mean ----------------
    for (int vb = blockIdx.x; vb < 200; vb += gridDim.x) {
        int gid = vb * 240 + tid;         // 200*240 = 48000 = N_PROT*6
        float s = 0.f;
        if (tid < 240) {
#pragma unroll 8
            for (int sl = 0; sl < MSL; ++sl) s += partial[(size_t)sl * MPART_STRIDE + gid];
        }
        smem[tid] = s;
        __syncthreads();
        if (tid < 240) {
            int j = tid % 6;
            if (j < 5) {
                float cnt = smem[tid - j + 5];
                agg[(size_t)(gid / 6) * AGG_S + j] = s / fmaxf(cnt, 1.0f);
            }
        }
        __syncthreads();
    }
    grid.sync();

    // ---------------- Phase E: final gather-add ----------------
    for (int vb = blockIdx.x; vb < 782; vb += gridDim.x) {
        int l = vb * 256 + tid;
        if (l < N_LBL) {
            int s = lbl_src[l], d = lbl_dst[l];
            const float* dr = &drugO[(size_t)s * OUT_D];
            const float* pr = &protO[(size_t)d * OUT_D];
            const float* ag = &agg[(size_t)d * AGG_S];
            float4 m4 = *(const float4*)ag;
            float  m5 = ag[4];
            float* op = &out[(size_t)l * OUT_D];
            op[0] = dr[0] + pr[0] + m4.x;
            op[1] = dr[1] + pr[1] + m4.y;
            op[2] = dr[2] + pr[2] + m4.z;
            op[3] = dr[3] + pr[3] + m4.w;
            op[4] = dr[4] + pr[4] + m5;
        }
    }
}

// =========================================================================
// ============ LEGACY round-4 path (fallback if coop launch fails) ========
// =========================================================================
__global__ void k_fold(const float* __restrict__ W_l, const float* __restrict__ W_r,
                       const float* __restrict__ W_lin, const float* __restrict__ b_l,
                       float* __restrict__ A, float* __restrict__ B, float* __restrict__ c) {
    int t  = blockIdx.x * 256 + threadIdx.x;
    int e  = t >> 3;
    int j  = t & 7;
    int h0 = j * 64;
    const int nA = OUT_D * D_DRUG;
    const int nB = OUT_D * D_PROT;
    float s = 0.f;
    if (e < nA) {
        int o = e / D_DRUG, k = e - o * D_DRUG;
        const float* wp = W_lin + o * WLD + D_DRUG + h0;
        const float* w  = W_l + (size_t)h0 * D_DRUG + k;
#pragma unroll 8
        for (int h = 0; h < 64; ++h) s += wp[h] * w[h * D_DRUG];
    } else if (e < nA + nB) {
        int u = e - nA;
        int o = u / D_PROT, k = u - o * D_PROT;
        const float* wp = W_lin + o * WLD + D_DRUG + h0;
        const float* w  = W_r + (size_t)h0 * D_PROT + k;
#pragma unroll 8
        for (int h = 0; h < 64; ++h) s += wp[h] * w[h * D_PROT];
    } else if (e < nA + nB + OUT_D) {
        int o = e - nA - nB;
        const float* wp = W_lin + o * WLD + D_DRUG + h0;
#pragma unroll 8
        for (int h = 0; h < 64; ++h) s += wp[h] * b_l[h0 + h];
    }
    s += __shfl_xor(s, 1, 64);
    s += __shfl_xor(s, 2, 64);
    s += __shfl_xor(s, 4, 64);
    if (j == 0) {
        if (e < nA)                     A[e] = s;
        else if (e < nA + nB)           B[e - nA] = s;
        else if (e < nA + nB + OUT_D)   c[e - nA - nB] = s;
    }
}

__global__ void k_drug(const float* __restrict__ x_drug, const float* __restrict__ A,
                       const float* __restrict__ W_lin, const float* __restrict__ b_lin,
                       float* __restrict__ P_A, float* __restrict__ drugO) {
    int gid = blockIdx.x * 256 + threadIdx.x;
    int row = gid >> 4;
    int sub = threadIdx.x & 15;
    const float4* xr = (const float4*)(x_drug + (size_t)row * D_DRUG);
    float acc[10];
#pragma unroll
    for (int i = 0; i < 10; ++i) acc[i] = 0.f;
    for (int k = sub; k < D_DRUG / 4; k += 16) {
        float4 x = xr[k];
#pragma unroll
        for (int o = 0; o < OUT_D; ++o) {
            float4 a = ((const float4*)(A + o * D_DRUG))[k];
            acc[o] += x.x * a.x + x.y * a.y + x.z * a.z + x.w * a.w;
            float4 w = ((const float4*)(W_lin + o * WLD))[k];
            acc[5 + o] += x.x * w.x + x.y * w.y + x.z * w.z + x.w * w.w;
        }
    }
#pragma unroll
    for (int i = 0; i < 10; ++i) {
        float v = acc[i];
        for (int m = 8; m; m >>= 1) v += __shfl_xor(v, m, 64);
        acc[i] = v;
    }
    if (sub < OUT_D) {
        P_A[(size_t)row * PA_S + sub]    = acc[sub];
        drugO[(size_t)row * OUT_D + sub] = acc[5 + sub] + b_lin[sub];
    } else if (sub < PA_S) {
        P_A[(size_t)row * PA_S + sub] = 0.f;
    }
}

__global__ void k_scan_prot(const float* __restrict__ x_prot,
                            const int* __restrict__ edge_src, const int* __restrict__ edge_dst,
                            const float* __restrict__ B, const float* __restrict__ c,
                            const float* __restrict__ P_A, float* __restrict__ partial,
                            float* __restrict__ protO) {
    int b = blockIdx.x;
    if (b < SCAN_B) {
        __shared__ float lagg[PROT_PER_G * 6];
        int tid = threadIdx.x;
        for (int i = tid; i < PROT_PER_G * 6; i += 256) lagg[i] = 0.f;
        __syncthreads();
        int pg  = b >> 6;
        int sl  = b & 63;
        int plo = pg * PROT_PER_G;
        int e0  = sl * EDGE_PER_S;
        const int4* dst4 = (const int4*)edge_dst;
        const int4* src4 = (const int4*)edge_src;
#define ACCUM(dd, ss) do {                                                   \
            int _d = (dd) - plo;                                             \
            if ((unsigned)_d < (unsigned)PROT_PER_G) {                       \
                const float* pp = P_A + (size_t)(ss) * PA_S;                 \
                float4 p4 = *(const float4*)pp;                              \
                float  p5 = pp[4];                                           \
                float* L = lagg + _d * 6;                                    \
                atomicAdd(L + 0, p4.x);                                      \
                atomicAdd(L + 1, p4.y);                                      \
                atomicAdd(L + 2, p4.z);                                      \
                atomicAdd(L + 3, p4.w);                                      \
                atomicAdd(L + 4, p5);                                        \
                atomicAdd(L + 5, 1.0f);                                      \
            } } while (0)
#pragma unroll
        for (int it = 0; it < EDGE_PER_S / 1024; ++it) {
            int e = e0 + (it * 256 + tid) * 4;
            if (e < N_EDGE) {
                int4 d4 = dst4[e >> 2];
                int4 s4 = src4[e >> 2];
                ACCUM(d4.x, s4.x);
                ACCUM(d4.y, s4.y);
                ACCUM(d4.z, s4.z);
                ACCUM(d4.w, s4.w);
            }
        }
#undef ACCUM
        __syncthreads();
        float* pout = partial + (size_t)sl * PART_STRIDE + (size_t)plo * 6;
        for (int i = tid; i < PROT_PER_G * 6; i += 256) pout[i] = lagg[i];
    } else {
        int wave = ((b - SCAN_B) * 256 + threadIdx.x) >> 6;
        int lane = threadIdx.x & 63;
        const float4* xr = (const float4*)(x_prot + (size_t)wave * D_PROT);
        float acc[OUT_D] = {0.f, 0.f, 0.f, 0.f, 0.f};
        for (int k = lane; k < D_PROT / 4; k += 64) {
            float4 x = xr[k];
#pragma unroll
            for (int o = 0; o < OUT_D; ++o) {
                float4 bb = ((const float4*)(B + o * D_PROT))[k];
                acc[o] += x.x * bb.x + x.y * bb.y + x.z * bb.z + x.w * bb.w;
            }
        }
#pragma unroll
        for (int o = 0; o < OUT_D; ++o) {
            float v = acc[o];
            for (int off = 32; off; off >>= 1) v += __shfl_xor(v, off, 64);
            acc[o] = v;
        }
        if (lane < OUT_D) protO[(size_t)wave * OUT_D + lane] = acc[lane] + c[lane];
    }
}

__global__ void k_reduce(const float* __restrict__ partial, float* __restrict__ agg) {
    int tid = threadIdx.x;
    int gid = blockIdx.x * 240 + tid;
    float s = 0.f;
#pragma unroll 8
    for (int sl = 0; sl < ESLICES; ++sl) s += partial[(size_t)sl * PART_STRIDE + gid];
    __shared__ float tmp[240];
    tmp[tid] = s;
    __syncthreads();
    int j = tid % 6;
    if (j < 5) {
        float cnt = tmp[tid - j + 5];
        agg[(size_t)(gid / 6) * AGG_S + j] = s / fmaxf(cnt, 1.0f);
    }
}

__global__ void k_final(const int* __restrict__ lbl_src, const int* __restrict__ lbl_dst,
                        const float* __restrict__ drugO, const float* __restrict__ protO,
                        const float* __restrict__ agg, float* __restrict__ out) {
    int l = blockIdx.x * blockDim.x + threadIdx.x;
    if (l >= N_LBL) return;
    int s = lbl_src[l], d = lbl_dst[l];
    const float* dr = &drugO[(size_t)s * OUT_D];
    const float* pr = &protO[(size_t)d * OUT_D];
    const float* ag = &agg[(size_t)d * AGG_S];
    float4 m4 = *(const float4*)ag;
    float  m5 = ag[4];
    float* op = &out[(size_t)l * OUT_D];
    op[0] = dr[0] + pr[0] + m4.x;
    op[1] = dr[1] + pr[1] + m4.y;
    op[2] = dr[2] + pr[2] + m4.z;
    op[3] = dr[3] + pr[3] + m4.w;
    op[4] = dr[4] + pr[4] + m5;
}

extern "C" void kernel_launch(void* const* d_in, const int* in_sizes, int n_in,
                              void* d_out, int out_size, void* d_ws, size_t ws_size,
                              hipStream_t stream) {
    const float* x_drug   = (const float*)d_in[0];
    const float* x_prot   = (const float*)d_in[1];
    const int*   edge_src = (const int*)d_in[2];
    const int*   edge_dst = (const int*)d_in[3];
    const int*   lbl_src  = (const int*)d_in[4];
    const int*   lbl_dst  = (const int*)d_in[5];
    const float* W_l      = (const float*)d_in[6];
    const float* b_l      = (const float*)d_in[7];
    const float* W_r      = (const float*)d_in[8];
    const float* W_lin    = (const float*)d_in[9];
    const float* b_lin    = (const float*)d_in[10];
    float* out = (float*)d_out;

    // workspace layout (no zero-init needed; partials fully written each run)
    char* ws = (char*)d_ws;
    float* agg     = (float*)(ws + 0);          //   256,000 B (8000 x 8)
    float* A       = (float*)(ws + 256000);     //     6,000 B (5x300)
    float* B       = (float*)(ws + 262000);     //    25,600 B (5x1280)
    float* c       = (float*)(ws + 287600);     //        32 B
    float* P_A     = (float*)(ws + 287632);     //   640,000 B (20000 x 8, padded)
    float* drugO   = (float*)(ws + 927632);     //   400,000 B
    float* protO   = (float*)(ws + 1327632);    //   160,000 B
    float* partial = (float*)(ws + 1487632);    // 12,288,000 B (64 x 48000; mega uses 32)
    // total: 13,775,632 B

    void* args[] = {
        (void*)&x_drug, (void*)&x_prot, (void*)&edge_src, (void*)&edge_dst,
        (void*)&lbl_src, (void*)&lbl_dst, (void*)&W_l, (void*)&b_l,
        (void*)&W_r, (void*)&W_lin, (void*)&b_lin,
        (void*)&A, (void*)&B, (void*)&c, (void*)&P_A, (void*)&drugO,
        (void*)&protO, (void*)&partial, (void*)&agg, (void*)&out
    };
    hipError_t err = hipLaunchCooperativeKernel((void*)k_mega, dim3(MEGA_GRID),
                                                dim3(256), args, 0, stream);
    if (err != hipSuccess) {
        (void)hipGetLastError();   // clear sticky error; run proven 5-kernel path
        k_fold<<<248, 256, 0, stream>>>(W_l, W_r, W_lin, b_l, A, B, c);
        k_drug<<<1250, 256, 0, stream>>>(x_drug, A, W_lin, b_lin, P_A, drugO);
        k_scan_prot<<<SCAN_B + 2000, 256, 0, stream>>>(x_prot, edge_src, edge_dst,
                                                       B, c, P_A, partial, protO);
        k_reduce<<<200, 240, 0, stream>>>(partial, agg);
        k_final<<<(N_LBL + 255) / 256, 256, 0, stream>>>(lbl_src, lbl_dst, drugO,
                                                         protO, agg, out);
    }
}

// Round 6
// 163.815 us; speedup vs baseline: 3.5710x; 3.5710x over previous
//
#include <hip/hip_runtime.h>

#define N_DRUG 20000
#define N_PROT 8000
#define D_DRUG 300
#define D_PROT 1280
#define HIDDEN 512
#define OUT_D  5
#define N_EDGE 500000
#define N_LBL  200000
#define WLD    812        // W_lin leading dim (300+512)
#define AGG_S  8          // agg row stride (floats): [0..4]=mean, rest pad
#define PA_S   8          // P_A row stride (floats): 32B-aligned float4 gathers

// edge-scan decomposition: 16 protein groups x 64 edge slices = 1024 blocks
// (round-3 lesson: 256 blocks = 1 block/CU after the dense part drains ->
//  latency-bound at 2.4% HBM. 1024 blocks + int4 edge loads + only 8
//  iterations/thread keeps 16 waves/CU and short dependence chains.
//  round-5 lesson: do NOT fuse these dispatches with cg::grid.sync() --
//  the gfx950 grid barrier costs ~100us/sync vs ~2us dispatch gaps.)
#define PGROUPS 16
#define PROT_PER_G (N_PROT / PGROUPS)     // 500
#define ESLICES 64
#define EDGE_PER_S 8192                   // 64*8192 = 524288 >= N_EDGE (tail guarded)
#define SCAN_B (PGROUPS * ESLICES)        // 1024
#define PART_STRIDE (N_PROT * 6)          // 48000 floats per slice

// =========================================================================
// k0: fold A/B/c (no atomics: 8-lane shfl reduce over h-chunks).
// A[o,k]=sum_h Wlin_h[o,h]W_l[h,k]; B likewise from W_r; c=Wlin_h@b_l.
// =========================================================================
__global__ void k_fold(const float* __restrict__ W_l, const float* __restrict__ W_r,
                       const float* __restrict__ W_lin, const float* __restrict__ b_l,
                       float* __restrict__ A, float* __restrict__ B, float* __restrict__ c) {
    int t  = blockIdx.x * 256 + threadIdx.x;   // [0, 63488)
    int e  = t >> 3;                  // output element [0, 7936)
    int j  = t & 7;                   // h-chunk lane
    int h0 = j * 64;
    const int nA = OUT_D * D_DRUG;    // 1500
    const int nB = OUT_D * D_PROT;    // 6400
    float s = 0.f;
    if (e < nA) {
        int o = e / D_DRUG, k = e - o * D_DRUG;
        const float* wp = W_lin + o * WLD + D_DRUG + h0;
        const float* w  = W_l + (size_t)h0 * D_DRUG + k;
#pragma unroll 8
        for (int h = 0; h < 64; ++h) s += wp[h] * w[h * D_DRUG];
    } else if (e < nA + nB) {
        int u = e - nA;
        int o = u / D_PROT, k = u - o * D_PROT;
        const float* wp = W_lin + o * WLD + D_DRUG + h0;
        const float* w  = W_r + (size_t)h0 * D_PROT + k;
#pragma unroll 8
        for (int h = 0; h < 64; ++h) s += wp[h] * w[h * D_PROT];
    } else if (e < nA + nB + OUT_D) {
        int o = e - nA - nB;
        const float* wp = W_lin + o * WLD + D_DRUG + h0;
#pragma unroll 8
        for (int h = 0; h < 64; ++h) s += wp[h] * b_l[h0 + h];
    }
    s += __shfl_xor(s, 1, 64);
    s += __shfl_xor(s, 2, 64);
    s += __shfl_xor(s, 4, 64);
    if (j == 0) {
        if (e < nA)                     A[e] = s;
        else if (e < nA + nB)           B[e - nA] = s;
        else if (e < nA + nB + OUT_D)   c[e - nA - nB] = s;
    }
}

// =========================================================================
// k1: single x_drug pass -> P_A (stride-8, padded) and drugO (+ b_lin).
// 16 lanes per row; 1250 blocks * 256 / 16 = 20000 rows exactly.
// =========================================================================
__global__ void k_drug(const float* __restrict__ x_drug, const float* __restrict__ A,
                       const float* __restrict__ W_lin, const float* __restrict__ b_lin,
                       float* __restrict__ P_A, float* __restrict__ drugO) {
    int gid = blockIdx.x * 256 + threadIdx.x;
    int row = gid >> 4;
    int sub = threadIdx.x & 15;
    const float4* xr = (const float4*)(x_drug + (size_t)row * D_DRUG);  // 75 float4
    float acc[10];
#pragma unroll
    for (int i = 0; i < 10; ++i) acc[i] = 0.f;
    for (int k = sub; k < D_DRUG / 4; k += 16) {
        float4 x = xr[k];
#pragma unroll
        for (int o = 0; o < OUT_D; ++o) {
            float4 a = ((const float4*)(A + o * D_DRUG))[k];
            acc[o] += x.x * a.x + x.y * a.y + x.z * a.z + x.w * a.w;
            float4 w = ((const float4*)(W_lin + o * WLD))[k];
            acc[5 + o] += x.x * w.x + x.y * w.y + x.z * w.z + x.w * w.w;
        }
    }
#pragma unroll
    for (int i = 0; i < 10; ++i) {
        float v = acc[i];
        for (int m = 8; m; m >>= 1) v += __shfl_xor(v, m, 64);
        acc[i] = v;
    }
    if (sub < OUT_D) {
        P_A[(size_t)row * PA_S + sub]    = acc[sub];
        drugO[(size_t)row * OUT_D + sub] = acc[5 + sub] + b_lin[sub];
    } else if (sub < PA_S) {
        P_A[(size_t)row * PA_S + sub] = 0.f;   // pad so float4 gathers are clean
    }
}

// =========================================================================
// k2: blocked edge-scan aggregation, NO global atomics at all.
//   blocks [0,1024):       (pg = b>>6, sl = b&63): stream 8192 edges of the
//                          slice as int4 pairs (both src+dst, coalesced, L2),
//                          filter dst in [plo,plo+500), gather P_A[src] (32B,
//                          L2-resident), accumulate into 12KB LDS, then
//                          plain-store the 3000-float partial (coalesced).
//   blocks [1024,3024):    protO = x_prot@B.T + c   (64 lanes/row)
// =========================================================================
__global__ void k_scan_prot(const float* __restrict__ x_prot,
                            const int* __restrict__ edge_src, const int* __restrict__ edge_dst,
                            const float* __restrict__ B, const float* __restrict__ c,
                            const float* __restrict__ P_A, float* __restrict__ partial,
                            float* __restrict__ protO) {
    int b = blockIdx.x;
    if (b < SCAN_B) {
        __shared__ float lagg[PROT_PER_G * 6];   // 12 KB
        int tid = threadIdx.x;
        for (int i = tid; i < PROT_PER_G * 6; i += 256) lagg[i] = 0.f;
        __syncthreads();

        int pg  = b >> 6;                 // protein group [0,16)
        int sl  = b & 63;                 // edge slice [0,64)
        int plo = pg * PROT_PER_G;
        int e0  = sl * EDGE_PER_S;
        const int4* dst4 = (const int4*)edge_dst;
        const int4* src4 = (const int4*)edge_src;

#define ACCUM(dd, ss) do {                                                   \
            int _d = (dd) - plo;                                             \
            if ((unsigned)_d < (unsigned)PROT_PER_G) {                       \
                const float* pp = P_A + (size_t)(ss) * PA_S;                 \
                float4 p4 = *(const float4*)pp;                              \
                float  p5 = pp[4];                                           \
                float* L = lagg + _d * 6;                                    \
                atomicAdd(L + 0, p4.x);                                      \
                atomicAdd(L + 1, p4.y);                                      \
                atomicAdd(L + 2, p4.z);                                      \
                atomicAdd(L + 3, p4.w);                                      \
                atomicAdd(L + 4, p5);                                        \
                atomicAdd(L + 5, 1.0f);                                      \
            } } while (0)

#pragma unroll
        for (int it = 0; it < EDGE_PER_S / 1024; ++it) {    // 8 iterations
            int e = e0 + (it * 256 + tid) * 4;
            if (e < N_EDGE) {            // N_EDGE % 4 == 0: whole int4 in or out
                int4 d4 = dst4[e >> 2];
                int4 s4 = src4[e >> 2];
                ACCUM(d4.x, s4.x);
                ACCUM(d4.y, s4.y);
                ACCUM(d4.z, s4.z);
                ACCUM(d4.w, s4.w);
            }
        }
#undef ACCUM
        __syncthreads();
        float* pout = partial + (size_t)sl * PART_STRIDE + (size_t)plo * 6;
        for (int i = tid; i < PROT_PER_G * 6; i += 256) pout[i] = lagg[i];
    } else {
        int wave = ((b - SCAN_B) * 256 + threadIdx.x) >> 6;  // 2000*256/64 = 8000
        int lane = threadIdx.x & 63;
        const float4* xr = (const float4*)(x_prot + (size_t)wave * D_PROT);  // 320 float4
        float acc[OUT_D] = {0.f, 0.f, 0.f, 0.f, 0.f};
        for (int k = lane; k < D_PROT / 4; k += 64) {
            float4 x = xr[k];
#pragma unroll
            for (int o = 0; o < OUT_D; ++o) {
                float4 bb = ((const float4*)(B + o * D_PROT))[k];
                acc[o] += x.x * bb.x + x.y * bb.y + x.z * bb.z + x.w * bb.w;
            }
        }
#pragma unroll
        for (int o = 0; o < OUT_D; ++o) {
            float v = acc[o];
            for (int off = 32; off; off >>= 1) v += __shfl_xor(v, off, 64);
            acc[o] = v;
        }
        if (lane < OUT_D) protO[(size_t)wave * OUT_D + lane] = acc[lane] + c[lane];
    }
}

// =========================================================================
// k2b: reduce the 64 slice-partials and bake in the mean division.
// 200 blocks x 240 threads = 48000 = N_PROT*6 (prot = gid/6, j = gid%6).
// Reads are coalesced per slice (consecutive gid -> consecutive addr).
// =========================================================================
__global__ void k_reduce(const float* __restrict__ partial, float* __restrict__ agg) {
    int tid = threadIdx.x;                 // [0,240)
    int gid = blockIdx.x * 240 + tid;      // [0,48000)
    float s = 0.f;
#pragma unroll 8
    for (int sl = 0; sl < ESLICES; ++sl) s += partial[(size_t)sl * PART_STRIDE + gid];
    __shared__ float tmp[240];
    tmp[tid] = s;
    __syncthreads();
    int j = tid % 6;
    if (j < 5) {
        float cnt = tmp[tid - j + 5];      // count lives at j==5 of same protein
        agg[(size_t)(gid / 6) * AGG_S + j] = s / fmaxf(cnt, 1.0f);
    }
}

// =========================================================================
// k3: final gather-add; agg holds the per-protein MEAN already.
// out[l] = drugO[s] + protO[d] + mean[d]   (b_lin already folded into drugO)
// =========================================================================
__global__ void k_final(const int* __restrict__ lbl_src, const int* __restrict__ lbl_dst,
                        const float* __restrict__ drugO, const float* __restrict__ protO,
                        const float* __restrict__ agg, float* __restrict__ out) {
    int l = blockIdx.x * blockDim.x + threadIdx.x;
    if (l >= N_LBL) return;
    int s = lbl_src[l], d = lbl_dst[l];
    const float* dr = &drugO[(size_t)s * OUT_D];
    const float* pr = &protO[(size_t)d * OUT_D];
    const float* ag = &agg[(size_t)d * AGG_S];
    float4 m4 = *(const float4*)ag;       // mean 0..3
    float  m5 = ag[4];                    // mean 4
    float* op = &out[(size_t)l * OUT_D];
    op[0] = dr[0] + pr[0] + m4.x;
    op[1] = dr[1] + pr[1] + m4.y;
    op[2] = dr[2] + pr[2] + m4.z;
    op[3] = dr[3] + pr[3] + m4.w;
    op[4] = dr[4] + pr[4] + m5;
}

extern "C" void kernel_launch(void* const* d_in, const int* in_sizes, int n_in,
                              void* d_out, int out_size, void* d_ws, size_t ws_size,
                              hipStream_t stream) {
    const float* x_drug   = (const float*)d_in[0];
    const float* x_prot   = (const float*)d_in[1];
    const int*   edge_src = (const int*)d_in[2];
    const int*   edge_dst = (const int*)d_in[3];
    const int*   lbl_src  = (const int*)d_in[4];
    const int*   lbl_dst  = (const int*)d_in[5];
    const float* W_l      = (const float*)d_in[6];
    const float* b_l      = (const float*)d_in[7];
    const float* W_r      = (const float*)d_in[8];
    const float* W_lin    = (const float*)d_in[9];
    const float* b_lin    = (const float*)d_in[10];
    float* out = (float*)d_out;

    // workspace layout (no zero-init needed anywhere; partials fully written)
    char* ws = (char*)d_ws;
    float* agg     = (float*)(ws + 0);          //   256,000 B (8000 x 8)
    float* A       = (float*)(ws + 256000);     //     6,000 B (5x300)
    float* B       = (float*)(ws + 262000);     //    25,600 B (5x1280)
    float* c       = (float*)(ws + 287600);     //        32 B
    float* P_A     = (float*)(ws + 287632);     //   640,000 B (20000 x 8, padded)
    float* drugO   = (float*)(ws + 927632);     //   400,000 B
    float* protO   = (float*)(ws + 1327632);    //   160,000 B
    float* partial = (float*)(ws + 1487632);    // 12,288,000 B (64 x 48000)
    // total: 13,775,632 B

    k_fold<<<248, 256, 0, stream>>>(W_l, W_r, W_lin, b_l, A, B, c);
    k_drug<<<1250, 256, 0, stream>>>(x_drug, A, W_lin, b_lin, P_A, drugO);
    k_scan_prot<<<SCAN_B + 2000, 256, 0, stream>>>(x_prot, edge_src, edge_dst,
                                                   B, c, P_A, partial, protO);
    k_reduce<<<200, 240, 0, stream>>>(partial, agg);
    k_final<<<(N_LBL + 255) / 256, 256, 0, stream>>>(lbl_src, lbl_dst, drugO, protO, agg, out);
}